// Round 9
// baseline (184.377 us; speedup 1.0000x reference)
//
#include <hip/hip_runtime.h>
#include <hip/hip_bf16.h>
#include <math.h>

#define B 4
#define C 256
#define G 8
#define N 4096
#define EPSV 1e-5f
#define SCALE 0.0625f   // 1/sqrt(256)

typedef __attribute__((ext_vector_type(8))) short short8;
typedef __attribute__((ext_vector_type(16))) float f32x16;
typedef unsigned short ushort_t;
typedef unsigned int uint_t;

// ---- bf16 helpers (bit-level, RNE) ----
__device__ __forceinline__ ushort_t f2bf(float f) {
    union { float f; uint_t u; } c; c.f = f;
    uint_t u = c.u;
    uint_t r = (u + 0x7FFFu + ((u >> 16) & 1u)) >> 16;
    return (ushort_t)r;
}
__device__ __forceinline__ float bf2f(ushort_t h) {
    union { uint_t u; float f; } c; c.u = ((uint_t)h) << 16;
    return c.f;
}
__device__ __forceinline__ uint_t pack2(float a, float b) {
    return (uint_t)f2bf(a) | ((uint_t)f2bf(b) << 16);
}
__device__ __forceinline__ uint_t cvtpk_bf16(float lo, float hi) {
    uint_t r;
    asm("v_cvt_pk_bf16_f32 %0, %1, %2" : "=v"(r) : "v"(lo), "v"(hi));
    return r;
}
__device__ __forceinline__ void gl_lds16(const void* g, void* l) {
    __builtin_amdgcn_global_load_lds(
        (const __attribute__((address_space(1))) void*)g,
        (__attribute__((address_space(3))) void*)l, 16, 0, 0);
}

// ---------------- K0: weights fp32 -> bf16 (w_qkv ++ w_proj) ----------------
__global__ __launch_bounds__(256) void wconv(const float* __restrict__ wq,
        const float* __restrict__ wp, ushort_t* __restrict__ wbf) {
    int idx = blockIdx.x*256 + threadIdx.x;
    #pragma unroll
    for (int p = 0; p < 4; p++) {
        int id = idx + p*16384;
        float4 v = (id < 49152) ? ((const float4*)wq)[id] : ((const float4*)wp)[id - 49152];
        uint2 pk; pk.x = pack2(v.x, v.y); pk.y = pack2(v.z, v.w);
        *(uint2*)&wbf[(size_t)id*4] = pk;
    }
}

// ---------------- K1a: groupnorm partial sums ----------------
__global__ __launch_bounds__(256) void gn_partial(const float* __restrict__ x,
                                                  float* __restrict__ partials) {
    int blk = blockIdx.x;
    int bg = blk >> 3;
    int part = blk & 7;
    const float4* xp4 = (const float4*)(x + (size_t)bg * (32 * N) + (size_t)part * (32 * N / 8));
    float s = 0.f, ss = 0.f;
    for (int i = threadIdx.x; i < 4096; i += 256) {
        float4 v = xp4[i];
        s  += v.x + v.y + v.z + v.w;
        ss += v.x*v.x + v.y*v.y + v.z*v.z + v.w*v.w;
    }
    __shared__ float rs[256], rss[256];
    rs[threadIdx.x] = s; rss[threadIdx.x] = ss;
    __syncthreads();
    for (int off = 128; off > 0; off >>= 1) {
        if (threadIdx.x < off) {
            rs[threadIdx.x]  += rs[threadIdx.x + off];
            rss[threadIdx.x] += rss[threadIdx.x + off];
        }
        __syncthreads();
    }
    if (threadIdx.x == 0) {
        partials[(bg*8 + part)*2]     = rs[0];
        partials[(bg*8 + part)*2 + 1] = rss[0];
    }
}

// ---------------- K1b: finalize mu/rstd ----------------
__global__ void gn_final(const float* __restrict__ partials, float* __restrict__ stats) {
    int t = threadIdx.x;
    if (t < 32) {
        float s = 0.f, ss = 0.f;
        for (int p = 0; p < 8; p++) {
            s  += partials[(t*8 + p)*2];
            ss += partials[(t*8 + p)*2 + 1];
        }
        const float inv = 1.f / 131072.f;
        float mu = s * inv;
        float var = fmaxf(ss * inv - mu*mu, 0.f);
        stats[t*2]     = mu;
        stats[t*2 + 1] = rsqrtf(var + EPSV);
    }
}

// ---------------- K1c: normalize + transpose -> hbf[b][n][c] bf16 ----------------
__global__ __launch_bounds__(256) void norm_bf16(const float* __restrict__ x,
        const float* __restrict__ gamma, const float* __restrict__ beta,
        const float* __restrict__ stats, ushort_t* __restrict__ hbf) {
    int b = blockIdx.z, c0 = blockIdx.y*64, n0 = blockIdx.x*64;
    int t = threadIdx.x;
    int cq = t >> 4, nq = t & 15;
    ushort_t hv[4][4];
    #pragma unroll
    for (int i = 0; i < 4; i++) {
        int c = c0 + cq*4 + i;
        int g = c >> 5;
        float mu = stats[(b*G+g)*2], rs = stats[(b*G+g)*2+1];
        float ga = gamma[c]*rs;
        float be = beta[c] - mu*ga;
        float4 v = *(const float4*)&x[((size_t)(b*C + c))*N + n0 + nq*4];
        hv[i][0] = f2bf(v.x*ga + be);
        hv[i][1] = f2bf(v.y*ga + be);
        hv[i][2] = f2bf(v.z*ga + be);
        hv[i][3] = f2bf(v.w*ga + be);
    }
    #pragma unroll
    for (int j = 0; j < 4; j++) {
        uint2 pk;
        pk.x = (uint_t)hv[0][j] | ((uint_t)hv[1][j]<<16);
        pk.y = (uint_t)hv[2][j] | ((uint_t)hv[3][j]<<16);
        *(uint2*)&hbf[((size_t)(b*N + n0 + nq*4 + j))*256 + c0 + cq*4] = pk;
    }
}

// ---------------- K2: QKV GEMM, bf16 MFMA ----------------
__global__ __launch_bounds__(256) void qkv_mfma(const ushort_t* __restrict__ hbf,
        const ushort_t* __restrict__ wbf, const float* __restrict__ bias,
        ushort_t* __restrict__ qbf, ushort_t* __restrict__ kimg, ushort_t* __restrict__ vimg) {
    int b = blockIdx.z, o0 = blockIdx.y*128, n0 = blockIdx.x*128;
    int tid = threadIdx.x;
    int w = tid>>6, l = tid&63, l31 = l&31, lh = l>>5;
    __shared__ short Ws[2][8192];
    __shared__ short Hs[2][8192];

    const ushort_t* wb = wbf + (size_t)o0*256;
    const ushort_t* hb = hbf + ((size_t)b*N + n0)*256;

    auto stage = [&](int bb, int c0) {
        #pragma unroll
        for (int q = 0; q < 4; q++) {
            int u0 = (q*4 + w)*64;
            int u  = u0 + l;
            int row = u & 127, ch = u >> 7;
            gl_lds16(wb + (size_t)row*256 + c0 + ch*8, &Ws[bb][u0*8]);
            gl_lds16(hb + (size_t)row*256 + c0 + ch*8, &Hs[bb][u0*8]);
        }
    };

    f32x16 acc[4];
    #pragma unroll
    for (int nf = 0; nf < 4; nf++)
        #pragma unroll
        for (int r = 0; r < 16; r++) acc[nf][r] = 0.f;

    stage(0, 0);
    __syncthreads();
    for (int t = 0; t < 4; t++) {
        int bb = t & 1;
        if (t < 3) stage(bb^1, (t+1)*64);
        short8 af[4];
        #pragma unroll
        for (int s = 0; s < 4; s++)
            af[s] = *(const short8*)&Ws[bb][((2*s+lh)*128 + w*32 + l31)*8];
        #pragma unroll
        for (int nf = 0; nf < 4; nf++) {
            #pragma unroll
            for (int s = 0; s < 4; s++) {
                short8 hf = *(const short8*)&Hs[bb][((2*s+lh)*128 + nf*32 + l31)*8];
                acc[nf] = __builtin_amdgcn_mfma_f32_32x32x16_bf16(af[s], hf, acc[nf], 0, 0, 0);
            }
        }
        __syncthreads();
    }

    int ow = o0 + w*32;
    float bv[16];
    #pragma unroll
    for (int r = 0; r < 16; r++) bv[r] = bias[ow + (r&3) + 8*(r>>2) + 4*lh];

    if (ow < 256) {            // ---- Q: row-major, pre-scaled ----
        #pragma unroll
        for (int nf = 0; nf < 4; nf++) {
            int n = n0 + nf*32 + l31;
            ushort_t* row = qbf + ((size_t)(b*N + n))*256 + ow;
            #pragma unroll
            for (int rp = 0; rp < 8; rp++) {
                int r0 = rp*2;
                int cl = (r0&3) + 8*(r0>>2) + 4*lh;
                uint_t wd = cvtpk_bf16((acc[nf][r0]+bv[r0])*SCALE, (acc[nf][r0+1]+bv[r0+1])*SCALE);
                *(uint_t*)(row + cl) = wd;
            }
        }
    } else if (ow < 512) {     // ---- K: LDS-image blocked ----
        int cb = ow - 256;
        #pragma unroll
        for (int nf = 0; nf < 4; nf++) {
            int n = n0 + nf*32 + l31;
            ushort_t* tbase = kimg + (size_t)b*1048576 + (size_t)(n>>5)*8192
                            + (size_t)l31*8 + 4*lh;
            #pragma unroll
            for (int g = 0; g < 4; g++) {
                uint2 pk;
                pk.x = pack2(acc[nf][g*4+0]+bv[g*4+0], acc[nf][g*4+1]+bv[g*4+1]);
                pk.y = pack2(acc[nf][g*4+2]+bv[g*4+2], acc[nf][g*4+3]+bv[g*4+3]);
                *(uint2*)(tbase + (size_t)((cb>>3)+g)*256) = pk;
            }
        }
    } else {                   // ---- V: LDS-image blocked ----
        int cb = ow - 512;
        #pragma unroll
        for (int nf = 0; nf < 4; nf++) {
            int n = n0 + nf*32 + l31;
            ushort_t* tbase = vimg + (size_t)b*1048576 + (size_t)(n>>5)*8192
                            + (size_t)(l31>>3)*2048 + (l31&7);
            #pragma unroll
            for (int r = 0; r < 16; r++) {
                int cl = (r&3) + 8*(r>>2) + 4*lh;
                tbase[(size_t)(cb+cl)*8] = f2bf(acc[nf][r] + bv[r]);
            }
        }
    }
}

// ---------------- K3: MFMA flash attention, c-split wave pairs ----------------
// grid 512: f -> {qt 0..63, b, kvh}; XCD (f&7) owns one (b,kvh) KV set; 2 blocks/CU.
// Wave pair shares a 32-row q tile: both compute QK^T (dup), each owns 128 V cols.
__global__ __launch_bounds__(256, 2) void attn_mfma(const ushort_t* __restrict__ qbf,
        const ushort_t* __restrict__ kimg, const ushort_t* __restrict__ vimg,
        ushort_t* __restrict__ part, float* __restrict__ ml) {
    int f = blockIdx.x;
    int qt  = f >> 3;
    int b   = (f >> 1) & 3;
    int kvh = f & 1;
    constexpr int NT = 64;   // 2048 kv rows / 32
    int w = threadIdx.x >> 6;
    int l = threadIdx.x & 63;
    int l31 = l & 31, lh = l >> 5;
    int qsub = w >> 1;       // q tile within block
    int chv  = w & 1;        // PV column half

    __shared__ short KV[2][2][8192];   // [slot][K/V][16B-unit LDS image]

    int qbase = qt*64 + qsub*32;
    short8 qf[16];
    {
        const ushort_t* qrow = qbf + ((size_t)(b*N + qbase + l31))*256;
        #pragma unroll
        for (int s = 0; s < 16; s++)
            qf[s] = *(const short8*)(qrow + s*16 + lh*8);
    }

    f32x16 ot[4];            // O columns chv*128 + mc*32
    #pragma unroll
    for (int mc = 0; mc < 4; mc++)
        #pragma unroll
        for (int r = 0; r < 16; r++) ot[mc][r] = 0.f;
    float m = -INFINITY, lsum = 0.f;

    const char* kbase = (const char*)kimg + (size_t)b*2097152;
    const char* vbase = (const char*)vimg + (size_t)b*2097152;

    auto stage = [&](int slot, int t) {
        int tile = kvh*64 + t;
        const char* kt = kbase + (size_t)tile*16384;
        const char* vt = vbase + (size_t)tile*16384;
        #pragma unroll
        for (int q = 0; q < 4; q++) {
            int u0 = (w*4 + q)*64;
            gl_lds16(kt + (u0 + l)*16, &KV[slot][0][u0*8]);
            gl_lds16(vt + (u0 + l)*16, &KV[slot][1][u0*8]);
        }
    };

    stage(0, 0);

    for (int t = 0; t < NT; t++) {
        int slot = t & 1;
        __syncthreads();                 // stage(t) complete; prev reads of slot^1 done
        if (t+1 < NT) stage(slot^1, t+1);

        // ---- QK^T (duplicated within wave pair) ----
        f32x16 st0, st1;
        #pragma unroll
        for (int r = 0; r < 16; r++) { st0[r] = 0.f; st1[r] = 0.f; }
        const short* kb_ = &KV[slot][0][0];
        __builtin_amdgcn_s_setprio(1);
        #pragma unroll
        for (int s = 0; s < 8; s++) {
            short8 ka = *(const short8*)(kb_ + ((size_t)((4*s   + lh)*32 + l31))*8);
            short8 kc = *(const short8*)(kb_ + ((size_t)((4*s+2 + lh)*32 + l31))*8);
            st0 = __builtin_amdgcn_mfma_f32_32x32x16_bf16(ka, qf[2*s],   st0, 0, 0, 0);
            st1 = __builtin_amdgcn_mfma_f32_32x32x16_bf16(kc, qf[2*s+1], st1, 0, 0, 0);
        }
        __builtin_amdgcn_s_setprio(0);

        // ---- online softmax ----
        float sv[16];
        #pragma unroll
        for (int r = 0; r < 16; r++) sv[r] = st0[r] + st1[r];
        float pmax = sv[0];
        #pragma unroll
        for (int r = 1; r < 16; r++) pmax = fmaxf(pmax, sv[r]);
        pmax = fmaxf(pmax, __shfl_xor(pmax, 32));
        if (!__all(pmax <= m + 8.0f)) {  // defer-max (T13)
            float mn = fmaxf(m, pmax);
            float fac = __expf(m - mn);
            m = mn;
            lsum *= fac;
            #pragma unroll
            for (int mc = 0; mc < 4; mc++)
                #pragma unroll
                for (int r = 0; r < 16; r++) ot[mc][r] *= fac;
        }
        float p[16]; float ls = 0.f;
        #pragma unroll
        for (int r = 0; r < 16; r++) { p[r] = __expf(sv[r] - m); ls += p[r]; }
        ls += __shfl_xor(ls, 32);
        lsum += ls;

        // ---- P -> bf16 B-fragments (cvt_pk + permlane32_swap) ----
        short8 pf0, pf1;
        {
            uint_t x0 = cvtpk_bf16(p[0], p[1]);
            uint_t y0 = cvtpk_bf16(p[4], p[5]);
            uint_t x1 = cvtpk_bf16(p[2], p[3]);
            uint_t y1 = cvtpk_bf16(p[6], p[7]);
            auto r0 = __builtin_amdgcn_permlane32_swap(x0, y0, false, false);
            auto r1 = __builtin_amdgcn_permlane32_swap(x1, y1, false, false);
            union { uint_t u[4]; short8 s8; } u_;
            u_.u[0] = r0[0]; u_.u[1] = r1[0]; u_.u[2] = r0[1]; u_.u[3] = r1[1];
            pf0 = u_.s8;
            uint_t x2 = cvtpk_bf16(p[8],  p[9]);
            uint_t y2 = cvtpk_bf16(p[12], p[13]);
            uint_t x3 = cvtpk_bf16(p[10], p[11]);
            uint_t y3 = cvtpk_bf16(p[14], p[15]);
            auto r2 = __builtin_amdgcn_permlane32_swap(x2, y2, false, false);
            auto r3 = __builtin_amdgcn_permlane32_swap(x3, y3, false, false);
            union { uint_t u[4]; short8 s8; } u2_;
            u2_.u[0] = r2[0]; u2_.u[1] = r3[0]; u2_.u[2] = r2[1]; u2_.u[3] = r3[1];
            pf1 = u2_.s8;
        }

        // ---- PV: this wave's 128-column half ----
        const short* vb_ = &KV[slot][1][0];
        __builtin_amdgcn_s_setprio(1);
        #pragma unroll
        for (int mc = 0; mc < 4; mc++) {
            int cc = chv*4 + mc;
            short8 v0 = *(const short8*)(vb_ + ((size_t)((lh)*256   + cc*32 + l31))*8);
            short8 v1 = *(const short8*)(vb_ + ((size_t)((2+lh)*256 + cc*32 + l31))*8);
            ot[mc] = __builtin_amdgcn_mfma_f32_32x32x16_bf16(v0, pf0, ot[mc], 0, 0, 0);
            ot[mc] = __builtin_amdgcn_mfma_f32_32x32x16_bf16(v1, pf1, ot[mc], 0, 0, 0);
        }
        __builtin_amdgcn_s_setprio(0);
    }

    // ---- write normalized partial (bf16) + (m, lsum) ----
    float invl = 1.f / lsum;
    ushort_t* pbase = part + (size_t)kvh*4194304 + ((size_t)(b*N + qbase + l31))*256 + chv*128;
    #pragma unroll
    for (int mc = 0; mc < 4; mc++)
        #pragma unroll
        for (int rp = 0; rp < 8; rp++) {
            int r0 = rp*2;
            uint_t wd = cvtpk_bf16(ot[mc][r0]*invl, ot[mc][r0+1]*invl);
            int c0 = (r0 & 3) + 8*(r0 >> 2) + 4*lh + 32*mc;
            *(uint_t*)(pbase + c0) = wd;
        }
    if (chv == 0 && l < 32) {
        size_t row = (size_t)kvh*16384 + b*4096 + qbase + l;
        ml[row*2]     = m;
        ml[row*2 + 1] = lsum;
    }
}

// ---------------- K3b: merge kv-split halves ----------------
__global__ __launch_bounds__(256) void attn_merge(const ushort_t* __restrict__ part,
        const float* __restrict__ ml, ushort_t* __restrict__ ob) {
    int t = blockIdx.x*256 + threadIdx.x;
    int row = t >> 5;
    int c8 = (t & 31) * 8;
    float m0 = ml[(size_t)row*2],           l0 = ml[(size_t)row*2 + 1];
    float m1 = ml[(size_t)(16384 + row)*2], l1 = ml[(size_t)(16384 + row)*2 + 1];
    float M = fmaxf(m0, m1);
    float w0 = __expf(m0 - M) * l0, w1 = __expf(m1 - M) * l1;
    float inv = 1.f / (w0 + w1);
    w0 *= inv; w1 *= inv;
    const ushort_t* p0 = part + (size_t)row*256 + c8;
    const ushort_t* p1 = p0 + 4194304;
    float o[8];
    #pragma unroll
    for (int e = 0; e < 8; e++) o[e] = w0*bf2f(p0[e]) + w1*bf2f(p1[e]);
    uint4 pk;
    pk.x = pack2(o[0], o[1]);
    pk.y = pack2(o[2], o[3]);
    pk.z = pack2(o[4], o[5]);
    pk.w = pack2(o[6], o[7]);
    *(uint4*)(ob + (size_t)row*256 + c8) = pk;
}

// ---------------- K4: proj GEMM bf16 MFMA + bias + residual ----------------
__global__ __launch_bounds__(256) void proj_mfma(const ushort_t* __restrict__ obf,
        const ushort_t* __restrict__ wpbf, const float* __restrict__ bp,
        const float* __restrict__ x, float* __restrict__ out) {
    int b = blockIdx.z, o0 = blockIdx.y*128, n0 = blockIdx.x*128;
    int tid = threadIdx.x;
    int w = tid>>6, l = tid&63, l31 = l&31, lh = l>>5;
    __shared__ short Ws[2][8192];
    __shared__ short Hs[2][8192];

    const ushort_t* wb = wpbf + (size_t)o0*256;
    const ushort_t* hb = obf + ((size_t)b*N + n0)*256;

    auto stage = [&](int bb, int c0) {
        #pragma unroll
        for (int q = 0; q < 4; q++) {
            int u0 = (q*4 + w)*64;
            int u  = u0 + l;
            int row = u & 127, ch = u >> 7;
            gl_lds16(wb + (size_t)row*256 + c0 + ch*8, &Ws[bb][u0*8]);
            gl_lds16(hb + (size_t)row*256 + c0 + ch*8, &Hs[bb][u0*8]);
        }
    };

    f32x16 acc[4];
    #pragma unroll
    for (int nf = 0; nf < 4; nf++)
        #pragma unroll
        for (int r = 0; r < 16; r++) acc[nf][r] = 0.f;

    stage(0, 0);
    __syncthreads();
    for (int t = 0; t < 4; t++) {
        int bb = t & 1;
        if (t < 3) stage(bb^1, (t+1)*64);
        short8 af[4];
        #pragma unroll
        for (int s = 0; s < 4; s++)
            af[s] = *(const short8*)&Ws[bb][((2*s+lh)*128 + w*32 + l31)*8];
        #pragma unroll
        for (int nf = 0; nf < 4; nf++) {
            #pragma unroll
            for (int s = 0; s < 4; s++) {
                short8 hf = *(const short8*)&Hs[bb][((2*s+lh)*128 + nf*32 + l31)*8];
                acc[nf] = __builtin_amdgcn_mfma_f32_32x32x16_bf16(af[s], hf, acc[nf], 0, 0, 0);
            }
        }
        __syncthreads();
    }

    int cw = o0 + w*32;
    float bv[16];
    #pragma unroll
    for (int r = 0; r < 16; r++) bv[r] = bp[cw + (r&3) + 8*(r>>2) + 4*lh];

    #pragma unroll
    for (int nf = 0; nf < 4; nf++) {
        int n = n0 + nf*32 + l31;
        #pragma unroll
        for (int r = 0; r < 16; r++) {
            int cl = (r&3) + 8*(r>>2) + 4*lh;
            size_t a = ((size_t)b*C + cw + cl)*N + n;
            out[a] = acc[nf][r] + bv[r] + x[a];
        }
    }
}

extern "C" void kernel_launch(void* const* d_in, const int* in_sizes, int n_in,
                              void* d_out, int out_size, void* d_ws, size_t ws_size,
                              hipStream_t stream) {
    const float* x      = (const float*)d_in[0];
    const float* gamma  = (const float*)d_in[1];
    const float* beta   = (const float*)d_in[2];
    const float* w_qkv  = (const float*)d_in[3];
    const float* b_qkv  = (const float*)d_in[4];
    const float* w_proj = (const float*)d_in[5];
    const float* b_proj = (const float*)d_in[6];
    float* out = (float*)d_out;
    char* wsb  = (char*)d_ws;

    const size_t MB = 1048576;
    ushort_t* qbf  = (ushort_t*)(wsb);                       // 8 MB
    ushort_t* kimg = (ushort_t*)(wsb + 8*MB);                // 8 MB (LDS-image tiles)
    ushort_t* vimg = (ushort_t*)(wsb + 16*MB);               // 8 MB (LDS-image tiles)
    ushort_t* part = (ushort_t*)(wsb + 24*MB);               // 16 MB (2 halves)
    ushort_t* hbf  = part;                                   // aliases part (dead until attn)
    float*    ml   = (float*)  (wsb + 40*MB);                // 256 KB
    ushort_t* ob   = (ushort_t*)(wsb + 40*MB + 524288);      // 8 MB
    float* partials = (float*) (wsb + 48*MB + 524288);       // 2 KB
    float* stats    = partials + 512;
    ushort_t* wbf  = (ushort_t*)(wsb + 48*MB + 524288 + 4096); // 512 KB

    wconv<<<dim3(64), dim3(256), 0, stream>>>(w_qkv, w_proj, wbf);
    gn_partial<<<dim3(256), dim3(256), 0, stream>>>(x, partials);
    gn_final<<<dim3(1), dim3(64), 0, stream>>>(partials, stats);
    norm_bf16<<<dim3(64, 4, 4), dim3(256), 0, stream>>>(x, gamma, beta, stats, hbf);
    qkv_mfma<<<dim3(32, 6, 4), dim3(256), 0, stream>>>(hbf, wbf, b_qkv, qbf, kimg, vimg);
    attn_mfma<<<dim3(512), dim3(256), 0, stream>>>(qbf, kimg, vimg, part, ml);
    attn_merge<<<dim3(2048), dim3(256), 0, stream>>>(part, ml, ob);
    proj_mfma<<<dim3(32, 2, 4), dim3(256), 0, stream>>>(ob, wbf + 196608, b_proj, x, out);
}

// Round 10
// 151.303 us; speedup vs baseline: 1.2186x; 1.2186x over previous
//
#include <hip/hip_runtime.h>
#include <hip/hip_bf16.h>
#include <math.h>

#define B 4
#define C 256
#define G 8
#define N 4096
#define EPSV 1e-5f
#define SCALE 0.0625f   // 1/sqrt(256)

typedef __attribute__((ext_vector_type(8))) short short8;
typedef __attribute__((ext_vector_type(16))) float f32x16;
typedef unsigned short ushort_t;
typedef unsigned int uint_t;

// ---- bf16 helpers (bit-level, RNE) ----
__device__ __forceinline__ ushort_t f2bf(float f) {
    union { float f; uint_t u; } c; c.f = f;
    uint_t u = c.u;
    uint_t r = (u + 0x7FFFu + ((u >> 16) & 1u)) >> 16;
    return (ushort_t)r;
}
__device__ __forceinline__ float bf2f(ushort_t h) {
    union { uint_t u; float f; } c; c.u = ((uint_t)h) << 16;
    return c.f;
}
__device__ __forceinline__ uint_t pack2(float a, float b) {
    return (uint_t)f2bf(a) | ((uint_t)f2bf(b) << 16);
}
__device__ __forceinline__ uint_t cvtpk_bf16(float lo, float hi) {
    uint_t r;
    asm("v_cvt_pk_bf16_f32 %0, %1, %2" : "=v"(r) : "v"(lo), "v"(hi));
    return r;
}
__device__ __forceinline__ void gl_lds16(const void* g, void* l) {
    __builtin_amdgcn_global_load_lds(
        (const __attribute__((address_space(1))) void*)g,
        (__attribute__((address_space(3))) void*)l, 16, 0, 0);
}

// ---------------- K0: weights fp32 -> bf16 (w_qkv ++ w_proj) ----------------
__global__ __launch_bounds__(256) void wconv(const float* __restrict__ wq,
        const float* __restrict__ wp, ushort_t* __restrict__ wbf) {
    int idx = blockIdx.x*256 + threadIdx.x;
    #pragma unroll
    for (int p = 0; p < 4; p++) {
        int id = idx + p*16384;
        float4 v = (id < 49152) ? ((const float4*)wq)[id] : ((const float4*)wp)[id - 49152];
        uint2 pk; pk.x = pack2(v.x, v.y); pk.y = pack2(v.z, v.w);
        *(uint2*)&wbf[(size_t)id*4] = pk;
    }
}

// ---------------- K1a: groupnorm partial sums ----------------
__global__ __launch_bounds__(256) void gn_partial(const float* __restrict__ x,
                                                  float* __restrict__ partials) {
    int blk = blockIdx.x;
    int bg = blk >> 3;
    int part = blk & 7;
    const float4* xp4 = (const float4*)(x + (size_t)bg * (32 * N) + (size_t)part * (32 * N / 8));
    float s = 0.f, ss = 0.f;
    for (int i = threadIdx.x; i < 4096; i += 256) {
        float4 v = xp4[i];
        s  += v.x + v.y + v.z + v.w;
        ss += v.x*v.x + v.y*v.y + v.z*v.z + v.w*v.w;
    }
    __shared__ float rs[256], rss[256];
    rs[threadIdx.x] = s; rss[threadIdx.x] = ss;
    __syncthreads();
    for (int off = 128; off > 0; off >>= 1) {
        if (threadIdx.x < off) {
            rs[threadIdx.x]  += rs[threadIdx.x + off];
            rss[threadIdx.x] += rss[threadIdx.x + off];
        }
        __syncthreads();
    }
    if (threadIdx.x == 0) {
        partials[(bg*8 + part)*2]     = rs[0];
        partials[(bg*8 + part)*2 + 1] = rss[0];
    }
}

// ---------------- K1b: finalize mu/rstd ----------------
__global__ void gn_final(const float* __restrict__ partials, float* __restrict__ stats) {
    int t = threadIdx.x;
    if (t < 32) {
        float s = 0.f, ss = 0.f;
        for (int p = 0; p < 8; p++) {
            s  += partials[(t*8 + p)*2];
            ss += partials[(t*8 + p)*2 + 1];
        }
        const float inv = 1.f / 131072.f;
        float mu = s * inv;
        float var = fmaxf(ss * inv - mu*mu, 0.f);
        stats[t*2]     = mu;
        stats[t*2 + 1] = rsqrtf(var + EPSV);
    }
}

// ---------------- K1c: normalize + transpose -> hbf[b][n][c] bf16 ----------------
__global__ __launch_bounds__(256) void norm_bf16(const float* __restrict__ x,
        const float* __restrict__ gamma, const float* __restrict__ beta,
        const float* __restrict__ stats, ushort_t* __restrict__ hbf) {
    int b = blockIdx.z, c0 = blockIdx.y*64, n0 = blockIdx.x*64;
    int t = threadIdx.x;
    int cq = t >> 4, nq = t & 15;
    ushort_t hv[4][4];
    #pragma unroll
    for (int i = 0; i < 4; i++) {
        int c = c0 + cq*4 + i;
        int g = c >> 5;
        float mu = stats[(b*G+g)*2], rs = stats[(b*G+g)*2+1];
        float ga = gamma[c]*rs;
        float be = beta[c] - mu*ga;
        float4 v = *(const float4*)&x[((size_t)(b*C + c))*N + n0 + nq*4];
        hv[i][0] = f2bf(v.x*ga + be);
        hv[i][1] = f2bf(v.y*ga + be);
        hv[i][2] = f2bf(v.z*ga + be);
        hv[i][3] = f2bf(v.w*ga + be);
    }
    #pragma unroll
    for (int j = 0; j < 4; j++) {
        uint2 pk;
        pk.x = (uint_t)hv[0][j] | ((uint_t)hv[1][j]<<16);
        pk.y = (uint_t)hv[2][j] | ((uint_t)hv[3][j]<<16);
        *(uint2*)&hbf[((size_t)(b*N + n0 + nq*4 + j))*256 + c0 + cq*4] = pk;
    }
}

// ---------------- K2: QKV GEMM, bf16 MFMA ----------------
__global__ __launch_bounds__(256) void qkv_mfma(const ushort_t* __restrict__ hbf,
        const ushort_t* __restrict__ wbf, const float* __restrict__ bias,
        ushort_t* __restrict__ qbf, ushort_t* __restrict__ kimg, ushort_t* __restrict__ vimg) {
    int b = blockIdx.z, o0 = blockIdx.y*128, n0 = blockIdx.x*128;
    int tid = threadIdx.x;
    int w = tid>>6, l = tid&63, l31 = l&31, lh = l>>5;
    __shared__ short Ws[2][8192];
    __shared__ short Hs[2][8192];

    const ushort_t* wb = wbf + (size_t)o0*256;
    const ushort_t* hb = hbf + ((size_t)b*N + n0)*256;

    auto stage = [&](int bb, int c0) {
        #pragma unroll
        for (int q = 0; q < 4; q++) {
            int u0 = (q*4 + w)*64;
            int u  = u0 + l;
            int row = u & 127, ch = u >> 7;
            gl_lds16(wb + (size_t)row*256 + c0 + ch*8, &Ws[bb][u0*8]);
            gl_lds16(hb + (size_t)row*256 + c0 + ch*8, &Hs[bb][u0*8]);
        }
    };

    f32x16 acc[4];
    #pragma unroll
    for (int nf = 0; nf < 4; nf++)
        #pragma unroll
        for (int r = 0; r < 16; r++) acc[nf][r] = 0.f;

    stage(0, 0);
    __syncthreads();
    for (int t = 0; t < 4; t++) {
        int bb = t & 1;
        if (t < 3) stage(bb^1, (t+1)*64);
        short8 af[4];
        #pragma unroll
        for (int s = 0; s < 4; s++)
            af[s] = *(const short8*)&Ws[bb][((2*s+lh)*128 + w*32 + l31)*8];
        #pragma unroll
        for (int nf = 0; nf < 4; nf++) {
            #pragma unroll
            for (int s = 0; s < 4; s++) {
                short8 hf = *(const short8*)&Hs[bb][((2*s+lh)*128 + nf*32 + l31)*8];
                acc[nf] = __builtin_amdgcn_mfma_f32_32x32x16_bf16(af[s], hf, acc[nf], 0, 0, 0);
            }
        }
        __syncthreads();
    }

    int ow = o0 + w*32;
    float bv[16];
    #pragma unroll
    for (int r = 0; r < 16; r++) bv[r] = bias[ow + (r&3) + 8*(r>>2) + 4*lh];

    if (ow < 256) {            // ---- Q: row-major, pre-scaled ----
        #pragma unroll
        for (int nf = 0; nf < 4; nf++) {
            int n = n0 + nf*32 + l31;
            ushort_t* row = qbf + ((size_t)(b*N + n))*256 + ow;
            #pragma unroll
            for (int rp = 0; rp < 8; rp++) {
                int r0 = rp*2;
                int cl = (r0&3) + 8*(r0>>2) + 4*lh;
                uint_t wd = cvtpk_bf16((acc[nf][r0]+bv[r0])*SCALE, (acc[nf][r0+1]+bv[r0+1])*SCALE);
                *(uint_t*)(row + cl) = wd;
            }
        }
    } else if (ow < 512) {     // ---- K: LDS-image blocked ----
        int cb = ow - 256;
        #pragma unroll
        for (int nf = 0; nf < 4; nf++) {
            int n = n0 + nf*32 + l31;
            ushort_t* tbase = kimg + (size_t)b*1048576 + (size_t)(n>>5)*8192
                            + (size_t)l31*8 + 4*lh;
            #pragma unroll
            for (int g = 0; g < 4; g++) {
                uint2 pk;
                pk.x = pack2(acc[nf][g*4+0]+bv[g*4+0], acc[nf][g*4+1]+bv[g*4+1]);
                pk.y = pack2(acc[nf][g*4+2]+bv[g*4+2], acc[nf][g*4+3]+bv[g*4+3]);
                *(uint2*)(tbase + (size_t)((cb>>3)+g)*256) = pk;
            }
        }
    } else {                   // ---- V: LDS-image blocked ----
        int cb = ow - 512;
        #pragma unroll
        for (int nf = 0; nf < 4; nf++) {
            int n = n0 + nf*32 + l31;
            ushort_t* tbase = vimg + (size_t)b*1048576 + (size_t)(n>>5)*8192
                            + (size_t)(l31>>3)*2048 + (l31&7);
            #pragma unroll
            for (int r = 0; r < 16; r++) {
                int cl = (r&3) + 8*(r>>2) + 4*lh;
                tbase[(size_t)(cb+cl)*8] = f2bf(acc[nf][r] + bv[r]);
            }
        }
    }
}

// ---------------- K3: MFMA flash attention, kv4, 2 blocks/CU ----------------
// grid 512: f -> comb=f&15 {b,kvq}, qt=f>>4. XCD (f&7) holds 2 (b,kvq) KV sets
// (2MB <= 4MB L2). Each wave: 32 q rows, full 256 cols, QK computed once.
// __launch_bounds__(256,2) forces regs <= 256 (qf 64 VGPR + ot 128 AGPR + st 32).
__global__ __launch_bounds__(256, 2) void attn_mfma(const ushort_t* __restrict__ qbf,
        const ushort_t* __restrict__ kimg, const ushort_t* __restrict__ vimg,
        ushort_t* __restrict__ part, float* __restrict__ ml) {
    int f = blockIdx.x;
    int comb = f & 15;
    int qt  = f >> 4;
    int b   = comb >> 2;
    int kvq = comb & 3;
    constexpr int NT = 32;   // 1024 kv rows / 32
    int w = threadIdx.x >> 6;
    int l = threadIdx.x & 63;
    int l31 = l & 31, lh = l >> 5;

    __shared__ short KV[2][2][8192];   // [slot][K/V][16B-unit LDS image]

    int qbase = qt*128 + w*32;
    short8 qf[16];
    {
        const ushort_t* qrow = qbf + ((size_t)(b*N + qbase + l31))*256;
        #pragma unroll
        for (int s = 0; s < 16; s++)
            qf[s] = *(const short8*)(qrow + s*16 + lh*8);
    }

    f32x16 ot[8];
    #pragma unroll
    for (int mc = 0; mc < 8; mc++)
        #pragma unroll
        for (int r = 0; r < 16; r++) ot[mc][r] = 0.f;
    float m = -INFINITY, lsum = 0.f;

    const char* kbase = (const char*)kimg + (size_t)b*2097152;
    const char* vbase = (const char*)vimg + (size_t)b*2097152;

    auto stage = [&](int slot, int t) {
        int tile = kvq*32 + t;
        const char* kt = kbase + (size_t)tile*16384;
        const char* vt = vbase + (size_t)tile*16384;
        #pragma unroll
        for (int q = 0; q < 4; q++) {
            int u0 = (w*4 + q)*64;
            gl_lds16(kt + (u0 + l)*16, &KV[slot][0][u0*8]);
            gl_lds16(vt + (u0 + l)*16, &KV[slot][1][u0*8]);
        }
    };

    stage(0, 0);

    for (int t = 0; t < NT; t++) {
        int slot = t & 1;
        __syncthreads();                 // stage(t) complete; prev reads of slot^1 done
        if (t+1 < NT) stage(slot^1, t+1);

        // ---- QK^T ----
        f32x16 st0, st1;
        #pragma unroll
        for (int r = 0; r < 16; r++) { st0[r] = 0.f; st1[r] = 0.f; }
        const short* kb_ = &KV[slot][0][0];
        __builtin_amdgcn_s_setprio(1);
        #pragma unroll
        for (int s = 0; s < 8; s++) {
            short8 ka = *(const short8*)(kb_ + ((size_t)((4*s   + lh)*32 + l31))*8);
            short8 kc = *(const short8*)(kb_ + ((size_t)((4*s+2 + lh)*32 + l31))*8);
            st0 = __builtin_amdgcn_mfma_f32_32x32x16_bf16(ka, qf[2*s],   st0, 0, 0, 0);
            st1 = __builtin_amdgcn_mfma_f32_32x32x16_bf16(kc, qf[2*s+1], st1, 0, 0, 0);
        }
        __builtin_amdgcn_s_setprio(0);

        // ---- online softmax ----
        float sv[16];
        #pragma unroll
        for (int r = 0; r < 16; r++) sv[r] = st0[r] + st1[r];
        float pmax = sv[0];
        #pragma unroll
        for (int r = 1; r < 16; r++) pmax = fmaxf(pmax, sv[r]);
        pmax = fmaxf(pmax, __shfl_xor(pmax, 32));
        if (!__all(pmax <= m + 8.0f)) {  // defer-max (T13)
            float mn = fmaxf(m, pmax);
            float fac = __expf(m - mn);
            m = mn;
            lsum *= fac;
            #pragma unroll
            for (int mc = 0; mc < 8; mc++)
                #pragma unroll
                for (int r = 0; r < 16; r++) ot[mc][r] *= fac;
        }
        float p[16]; float ls = 0.f;
        #pragma unroll
        for (int r = 0; r < 16; r++) { p[r] = __expf(sv[r] - m); ls += p[r]; }
        ls += __shfl_xor(ls, 32);
        lsum += ls;

        // ---- P -> bf16 B-fragments (cvt_pk + permlane32_swap) ----
        short8 pf0, pf1;
        {
            uint_t x0 = cvtpk_bf16(p[0], p[1]);
            uint_t y0 = cvtpk_bf16(p[4], p[5]);
            uint_t x1 = cvtpk_bf16(p[2], p[3]);
            uint_t y1 = cvtpk_bf16(p[6], p[7]);
            auto r0 = __builtin_amdgcn_permlane32_swap(x0, y0, false, false);
            auto r1 = __builtin_amdgcn_permlane32_swap(x1, y1, false, false);
            union { uint_t u[4]; short8 s8; } u_;
            u_.u[0] = r0[0]; u_.u[1] = r1[0]; u_.u[2] = r0[1]; u_.u[3] = r1[1];
            pf0 = u_.s8;
            uint_t x2 = cvtpk_bf16(p[8],  p[9]);
            uint_t y2 = cvtpk_bf16(p[12], p[13]);
            uint_t x3 = cvtpk_bf16(p[10], p[11]);
            uint_t y3 = cvtpk_bf16(p[14], p[15]);
            auto r2 = __builtin_amdgcn_permlane32_swap(x2, y2, false, false);
            auto r3 = __builtin_amdgcn_permlane32_swap(x3, y3, false, false);
            union { uint_t u[4]; short8 s8; } u2_;
            u2_.u[0] = r2[0]; u2_.u[1] = r3[0]; u2_.u[2] = r2[1]; u2_.u[3] = r3[1];
            pf1 = u2_.s8;
        }

        // ---- PV ----
        const short* vb_ = &KV[slot][1][0];
        __builtin_amdgcn_s_setprio(1);
        #pragma unroll
        for (int mc = 0; mc < 8; mc++) {
            short8 v0 = *(const short8*)(vb_ + ((size_t)((lh)*256   + mc*32 + l31))*8);
            short8 v1 = *(const short8*)(vb_ + ((size_t)((2+lh)*256 + mc*32 + l31))*8);
            ot[mc] = __builtin_amdgcn_mfma_f32_32x32x16_bf16(v0, pf0, ot[mc], 0, 0, 0);
            ot[mc] = __builtin_amdgcn_mfma_f32_32x32x16_bf16(v1, pf1, ot[mc], 0, 0, 0);
        }
        __builtin_amdgcn_s_setprio(0);
    }

    // ---- write normalized partial (bf16) + (m, lsum) ----
    float invl = 1.f / lsum;
    ushort_t* pbase = part + (size_t)kvq*4194304 + ((size_t)(b*N + qbase + l31))*256;
    #pragma unroll
    for (int mc = 0; mc < 8; mc++)
        #pragma unroll
        for (int rp = 0; rp < 8; rp++) {
            int r0 = rp*2;
            uint_t wd = cvtpk_bf16(ot[mc][r0]*invl, ot[mc][r0+1]*invl);
            int c0 = (r0 & 3) + 8*(r0 >> 2) + 4*lh + 32*mc;
            *(uint_t*)(pbase + c0) = wd;
        }
    if (l < 32) {
        size_t row = (size_t)kvq*16384 + b*4096 + qbase + l;
        ml[row*2]     = m;
        ml[row*2 + 1] = lsum;
    }
}

// ---------------- K3b: merge kv-split partials ----------------
template<int NS>
__global__ __launch_bounds__(256) void attn_merge(const ushort_t* __restrict__ part,
        const float* __restrict__ ml, ushort_t* __restrict__ ob) {
    int t = blockIdx.x*256 + threadIdx.x;
    int row = t >> 5;
    int c8 = (t & 31) * 8;
    float mv[NS], lv[NS];
    float M = -INFINITY;
    #pragma unroll
    for (int i = 0; i < NS; i++) {
        mv[i] = ml[((size_t)i*16384 + row)*2];
        lv[i] = ml[((size_t)i*16384 + row)*2 + 1];
        M = fmaxf(M, mv[i]);
    }
    float wv[NS]; float wsum = 0.f;
    #pragma unroll
    for (int i = 0; i < NS; i++) { wv[i] = __expf(mv[i] - M)*lv[i]; wsum += wv[i]; }
    float inv = 1.f / wsum;
    float o[8];
    #pragma unroll
    for (int e = 0; e < 8; e++) o[e] = 0.f;
    #pragma unroll
    for (int i = 0; i < NS; i++) {
        const ushort_t* p = part + (size_t)i*4194304 + (size_t)row*256 + c8;
        float wi = wv[i]*inv;
        #pragma unroll
        for (int e = 0; e < 8; e++) o[e] += wi*bf2f(p[e]);
    }
    uint4 pk;
    pk.x = pack2(o[0], o[1]);
    pk.y = pack2(o[2], o[3]);
    pk.z = pack2(o[4], o[5]);
    pk.w = pack2(o[6], o[7]);
    *(uint4*)(ob + (size_t)row*256 + c8) = pk;
}

// ---------------- K4: proj GEMM bf16 MFMA + bias + residual ----------------
__global__ __launch_bounds__(256) void proj_mfma(const ushort_t* __restrict__ obf,
        const ushort_t* __restrict__ wpbf, const float* __restrict__ bp,
        const float* __restrict__ x, float* __restrict__ out) {
    int b = blockIdx.z, o0 = blockIdx.y*128, n0 = blockIdx.x*128;
    int tid = threadIdx.x;
    int w = tid>>6, l = tid&63, l31 = l&31, lh = l>>5;
    __shared__ short Ws[2][8192];
    __shared__ short Hs[2][8192];

    const ushort_t* wb = wpbf + (size_t)o0*256;
    const ushort_t* hb = obf + ((size_t)b*N + n0)*256;

    auto stage = [&](int bb, int c0) {
        #pragma unroll
        for (int q = 0; q < 4; q++) {
            int u0 = (q*4 + w)*64;
            int u  = u0 + l;
            int row = u & 127, ch = u >> 7;
            gl_lds16(wb + (size_t)row*256 + c0 + ch*8, &Ws[bb][u0*8]);
            gl_lds16(hb + (size_t)row*256 + c0 + ch*8, &Hs[bb][u0*8]);
        }
    };

    f32x16 acc[4];
    #pragma unroll
    for (int nf = 0; nf < 4; nf++)
        #pragma unroll
        for (int r = 0; r < 16; r++) acc[nf][r] = 0.f;

    stage(0, 0);
    __syncthreads();
    for (int t = 0; t < 4; t++) {
        int bb = t & 1;
        if (t < 3) stage(bb^1, (t+1)*64);
        short8 af[4];
        #pragma unroll
        for (int s = 0; s < 4; s++)
            af[s] = *(const short8*)&Ws[bb][((2*s+lh)*128 + w*32 + l31)*8];
        #pragma unroll
        for (int nf = 0; nf < 4; nf++) {
            #pragma unroll
            for (int s = 0; s < 4; s++) {
                short8 hf = *(const short8*)&Hs[bb][((2*s+lh)*128 + nf*32 + l31)*8];
                acc[nf] = __builtin_amdgcn_mfma_f32_32x32x16_bf16(af[s], hf, acc[nf], 0, 0, 0);
            }
        }
        __syncthreads();
    }

    int cw = o0 + w*32;
    float bv[16];
    #pragma unroll
    for (int r = 0; r < 16; r++) bv[r] = bp[cw + (r&3) + 8*(r>>2) + 4*lh];

    #pragma unroll
    for (int nf = 0; nf < 4; nf++) {
        int n = n0 + nf*32 + l31;
        #pragma unroll
        for (int r = 0; r < 16; r++) {
            int cl = (r&3) + 8*(r>>2) + 4*lh;
            size_t a = ((size_t)b*C + cw + cl)*N + n;
            out[a] = acc[nf][r] + bv[r] + x[a];
        }
    }
}

extern "C" void kernel_launch(void* const* d_in, const int* in_sizes, int n_in,
                              void* d_out, int out_size, void* d_ws, size_t ws_size,
                              hipStream_t stream) {
    const float* x      = (const float*)d_in[0];
    const float* gamma  = (const float*)d_in[1];
    const float* beta   = (const float*)d_in[2];
    const float* w_qkv  = (const float*)d_in[3];
    const float* b_qkv  = (const float*)d_in[4];
    const float* w_proj = (const float*)d_in[5];
    const float* b_proj = (const float*)d_in[6];
    float* out = (float*)d_out;
    char* wsb  = (char*)d_ws;

    const size_t MB = 1048576;
    ushort_t* qbf  = (ushort_t*)(wsb);                       // 8 MB
    ushort_t* kimg = (ushort_t*)(wsb + 8*MB);                // 8 MB (LDS-image tiles)
    ushort_t* vimg = (ushort_t*)(wsb + 16*MB);               // 8 MB (LDS-image tiles)
    ushort_t* part = (ushort_t*)(wsb + 24*MB);               // 32 MB (4 quarters)
    ushort_t* hbf  = part;                                   // aliases part (dead until attn)
    float*    ml   = (float*)  (wsb + 56*MB);                // 512 KB
    ushort_t* ob   = (ushort_t*)(wsb + 56*MB + 524288);      // 8 MB
    float* partials = (float*) (wsb + 64*MB + 524288);       // 2 KB
    float* stats    = partials + 512;
    ushort_t* wbf  = (ushort_t*)(wsb + 64*MB + 524288 + 4096); // 512 KB

    wconv<<<dim3(64), dim3(256), 0, stream>>>(w_qkv, w_proj, wbf);
    gn_partial<<<dim3(256), dim3(256), 0, stream>>>(x, partials);
    gn_final<<<dim3(1), dim3(64), 0, stream>>>(partials, stats);
    norm_bf16<<<dim3(64, 4, 4), dim3(256), 0, stream>>>(x, gamma, beta, stats, hbf);
    qkv_mfma<<<dim3(32, 6, 4), dim3(256), 0, stream>>>(hbf, wbf, b_qkv, qbf, kimg, vimg);
    attn_mfma<<<dim3(512), dim3(256), 0, stream>>>(qbf, kimg, vimg, part, ml);
    attn_merge<4><<<dim3(2048), dim3(256), 0, stream>>>(part, ml, ob);
    proj_mfma<<<dim3(32, 2, 4), dim3(256), 0, stream>>>(ob, wbf + 196608, b_proj, x, out);
}

// Round 11
// 137.236 us; speedup vs baseline: 1.3435x; 1.1025x over previous
//
#include <hip/hip_runtime.h>
#include <hip/hip_bf16.h>
#include <math.h>

#define B 4
#define C 256
#define G 8
#define N 4096
#define EPSV 1e-5f
#define SCALE 0.0625f   // 1/sqrt(256)

typedef __attribute__((ext_vector_type(8))) short short8;
typedef __attribute__((ext_vector_type(16))) float f32x16;
typedef unsigned short ushort_t;
typedef unsigned int uint_t;

// ---- bf16 helpers (bit-level, RNE) ----
__device__ __forceinline__ ushort_t f2bf(float f) {
    union { float f; uint_t u; } c; c.f = f;
    uint_t u = c.u;
    uint_t r = (u + 0x7FFFu + ((u >> 16) & 1u)) >> 16;
    return (ushort_t)r;
}
__device__ __forceinline__ float bf2f(ushort_t h) {
    union { uint_t u; float f; } c; c.u = ((uint_t)h) << 16;
    return c.f;
}
__device__ __forceinline__ uint_t pack2(float a, float b) {
    return (uint_t)f2bf(a) | ((uint_t)f2bf(b) << 16);
}
__device__ __forceinline__ uint_t cvtpk_bf16(float lo, float hi) {
    uint_t r;
    asm("v_cvt_pk_bf16_f32 %0, %1, %2" : "=v"(r) : "v"(lo), "v"(hi));
    return r;
}
__device__ __forceinline__ void gl_lds16(const void* g, void* l) {
    __builtin_amdgcn_global_load_lds(
        (const __attribute__((address_space(1))) void*)g,
        (__attribute__((address_space(3))) void*)l, 16, 0, 0);
}

// ---------------- K1: groupnorm partial sums ++ weight conversion ----------------
// blocks 0..255: gn partial sums; blocks 256..319: w_qkv++w_proj fp32->bf16.
__global__ __launch_bounds__(256) void gn_wconv(const float* __restrict__ x,
        float* __restrict__ partials, const float* __restrict__ wq,
        const float* __restrict__ wp, ushort_t* __restrict__ wbf) {
    int blk = blockIdx.x;
    if (blk < 256) {
        int bg = blk >> 3;
        int part = blk & 7;
        const float4* xp4 = (const float4*)(x + (size_t)bg * (32 * N) + (size_t)part * (32 * N / 8));
        float s = 0.f, ss = 0.f;
        for (int i = threadIdx.x; i < 4096; i += 256) {
            float4 v = xp4[i];
            s  += v.x + v.y + v.z + v.w;
            ss += v.x*v.x + v.y*v.y + v.z*v.z + v.w*v.w;
        }
        __shared__ float rs[256], rss[256];
        rs[threadIdx.x] = s; rss[threadIdx.x] = ss;
        __syncthreads();
        for (int off = 128; off > 0; off >>= 1) {
            if (threadIdx.x < off) {
                rs[threadIdx.x]  += rs[threadIdx.x + off];
                rss[threadIdx.x] += rss[threadIdx.x + off];
            }
            __syncthreads();
        }
        if (threadIdx.x == 0) {
            partials[(bg*8 + part)*2]     = rs[0];
            partials[(bg*8 + part)*2 + 1] = rss[0];
        }
    } else {
        int idx = (blk - 256)*256 + threadIdx.x;
        #pragma unroll
        for (int p = 0; p < 4; p++) {
            int id = idx + p*16384;
            float4 v = (id < 49152) ? ((const float4*)wq)[id] : ((const float4*)wp)[id - 49152];
            uint2 pk; pk.x = pack2(v.x, v.y); pk.y = pack2(v.z, v.w);
            *(uint2*)&wbf[(size_t)id*4] = pk;
        }
    }
}

// ---------------- K1b: finalize mu/rstd ----------------
__global__ void gn_final(const float* __restrict__ partials, float* __restrict__ stats) {
    int t = threadIdx.x;
    if (t < 32) {
        float s = 0.f, ss = 0.f;
        for (int p = 0; p < 8; p++) {
            s  += partials[(t*8 + p)*2];
            ss += partials[(t*8 + p)*2 + 1];
        }
        const float inv = 1.f / 131072.f;
        float mu = s * inv;
        float var = fmaxf(ss * inv - mu*mu, 0.f);
        stats[t*2]     = mu;
        stats[t*2 + 1] = rsqrtf(var + EPSV);
    }
}

// ---------------- K2: fused groupnorm + QKV GEMM, bf16 MFMA ----------------
// Reads x fp32 [c][n] directly; normalizes in regs; reg-stages bf16 H into the
// chunked LDS layout (unit16B[chunk=c/8][row=n]). W staged via global_load_lds.
__global__ __launch_bounds__(256) void qkv_fused(const float* __restrict__ x,
        const ushort_t* __restrict__ wbf, const float* __restrict__ gamma,
        const float* __restrict__ beta, const float* __restrict__ stats,
        const float* __restrict__ bias,
        ushort_t* __restrict__ qbf, ushort_t* __restrict__ kimg, ushort_t* __restrict__ vimg) {
    int b = blockIdx.z, o0 = blockIdx.y*128, n0 = blockIdx.x*128;
    int tid = threadIdx.x;
    int w = tid>>6, l = tid&63, l31 = l&31, lh = l>>5;
    int cg = tid >> 5;      // chunk 0..7 within K-step (8 c's)
    int nq = tid & 31;      // n-group of 4
    __shared__ short Ws[2][8192];
    __shared__ short Hs[2][8192];

    const ushort_t* wb = wbf + (size_t)o0*256;

    auto stageW = [&](int bb, int c0) {
        #pragma unroll
        for (int q = 0; q < 4; q++) {
            int u0 = (q*4 + w)*64;
            int u  = u0 + l;
            int row = u & 127, ch = u >> 7;
            gl_lds16(wb + (size_t)row*256 + c0 + ch*8, &Ws[bb][u0*8]);
        }
    };
    auto loadX = [&](int c0, float4* xv) {
        const float* xb = x + ((size_t)b*C + c0 + cg*8)*N + n0 + nq*4;
        #pragma unroll
        for (int e = 0; e < 8; e++)
            xv[e] = *(const float4*)(xb + (size_t)e*N);
    };
    auto writeH = [&](int bb, int c0, const float4* xv) {
        int cbase = c0 + cg*8;                 // chunk fully inside one 32-c group
        int g = cbase >> 5;
        float mu = stats[(b*G+g)*2], rs = stats[(b*G+g)*2+1];
        float ga[8], be[8];
        #pragma unroll
        for (int e = 0; e < 8; e++) {
            float gm = gamma[cbase+e];
            ga[e] = gm*rs;
            be[e] = beta[cbase+e] - mu*ga[e];
        }
        #pragma unroll
        for (int j = 0; j < 4; j++) {
            float h[8];
            #pragma unroll
            for (int e = 0; e < 8; e++) {
                float vx = (j==0) ? xv[e].x : (j==1) ? xv[e].y : (j==2) ? xv[e].z : xv[e].w;
                h[e] = vx*ga[e] + be[e];
            }
            uint4 pk;
            pk.x = pack2(h[0], h[1]);
            pk.y = pack2(h[2], h[3]);
            pk.z = pack2(h[4], h[5]);
            pk.w = pack2(h[6], h[7]);
            *(uint4*)&Hs[bb][(size_t)(cg*128 + nq*4 + j)*8] = pk;
        }
    };

    f32x16 acc[4];
    #pragma unroll
    for (int nf = 0; nf < 4; nf++)
        #pragma unroll
        for (int r = 0; r < 16; r++) acc[nf][r] = 0.f;

    float4 xv[8];
    loadX(0, xv);
    stageW(0, 0);
    writeH(0, 0, xv);
    __syncthreads();

    for (int t = 0; t < 4; t++) {
        int bb = t & 1;
        if (t < 3) { stageW(bb^1, (t+1)*64); loadX((t+1)*64, xv); }
        short8 af[4];
        #pragma unroll
        for (int s = 0; s < 4; s++)
            af[s] = *(const short8*)&Ws[bb][((2*s+lh)*128 + w*32 + l31)*8];
        #pragma unroll
        for (int nf = 0; nf < 4; nf++) {
            #pragma unroll
            for (int s = 0; s < 4; s++) {
                short8 hf = *(const short8*)&Hs[bb][((2*s+lh)*128 + nf*32 + l31)*8];
                acc[nf] = __builtin_amdgcn_mfma_f32_32x32x16_bf16(af[s], hf, acc[nf], 0, 0, 0);
            }
        }
        if (t < 3) writeH(bb^1, (t+1)*64, xv);
        __syncthreads();
    }

    int ow = o0 + w*32;
    float bv[16];
    #pragma unroll
    for (int r = 0; r < 16; r++) bv[r] = bias[ow + (r&3) + 8*(r>>2) + 4*lh];

    if (ow < 256) {            // ---- Q: row-major, pre-scaled ----
        #pragma unroll
        for (int nf = 0; nf < 4; nf++) {
            int n = n0 + nf*32 + l31;
            ushort_t* row = qbf + ((size_t)(b*N + n))*256 + ow;
            #pragma unroll
            for (int rp = 0; rp < 8; rp++) {
                int r0 = rp*2;
                int cl = (r0&3) + 8*(r0>>2) + 4*lh;
                uint_t wd = cvtpk_bf16((acc[nf][r0]+bv[r0])*SCALE, (acc[nf][r0+1]+bv[r0+1])*SCALE);
                *(uint_t*)(row + cl) = wd;
            }
        }
    } else if (ow < 512) {     // ---- K: LDS-image blocked ----
        int cb = ow - 256;
        #pragma unroll
        for (int nf = 0; nf < 4; nf++) {
            int n = n0 + nf*32 + l31;
            ushort_t* tbase = kimg + (size_t)b*1048576 + (size_t)(n>>5)*8192
                            + (size_t)l31*8 + 4*lh;
            #pragma unroll
            for (int g = 0; g < 4; g++) {
                uint2 pk;
                pk.x = pack2(acc[nf][g*4+0]+bv[g*4+0], acc[nf][g*4+1]+bv[g*4+1]);
                pk.y = pack2(acc[nf][g*4+2]+bv[g*4+2], acc[nf][g*4+3]+bv[g*4+3]);
                *(uint2*)(tbase + (size_t)((cb>>3)+g)*256) = pk;
            }
        }
    } else {                   // ---- V: LDS-image blocked ----
        int cb = ow - 512;
        #pragma unroll
        for (int nf = 0; nf < 4; nf++) {
            int n = n0 + nf*32 + l31;
            ushort_t* tbase = vimg + (size_t)b*1048576 + (size_t)(n>>5)*8192
                            + (size_t)(l31>>3)*2048 + (l31&7);
            #pragma unroll
            for (int r = 0; r < 16; r++) {
                int cl = (r&3) + 8*(r>>2) + 4*lh;
                tbase[(size_t)(cb+cl)*8] = f2bf(acc[nf][r] + bv[r]);
            }
        }
    }
}

// ---------------- K3: MFMA flash attention, kv4, 2 blocks/CU (unchanged) ----------------
__global__ __launch_bounds__(256, 2) void attn_mfma(const ushort_t* __restrict__ qbf,
        const ushort_t* __restrict__ kimg, const ushort_t* __restrict__ vimg,
        ushort_t* __restrict__ part, float* __restrict__ ml) {
    int f = blockIdx.x;
    int comb = f & 15;
    int qt  = f >> 4;
    int b   = comb >> 2;
    int kvq = comb & 3;
    constexpr int NT = 32;
    int w = threadIdx.x >> 6;
    int l = threadIdx.x & 63;
    int l31 = l & 31, lh = l >> 5;

    __shared__ short KV[2][2][8192];

    int qbase = qt*128 + w*32;
    short8 qf[16];
    {
        const ushort_t* qrow = qbf + ((size_t)(b*N + qbase + l31))*256;
        #pragma unroll
        for (int s = 0; s < 16; s++)
            qf[s] = *(const short8*)(qrow + s*16 + lh*8);
    }

    f32x16 ot[8];
    #pragma unroll
    for (int mc = 0; mc < 8; mc++)
        #pragma unroll
        for (int r = 0; r < 16; r++) ot[mc][r] = 0.f;
    float m = -INFINITY, lsum = 0.f;

    const char* kbase = (const char*)kimg + (size_t)b*2097152;
    const char* vbase = (const char*)vimg + (size_t)b*2097152;

    auto stage = [&](int slot, int t) {
        int tile = kvq*32 + t;
        const char* kt = kbase + (size_t)tile*16384;
        const char* vt = vbase + (size_t)tile*16384;
        #pragma unroll
        for (int q = 0; q < 4; q++) {
            int u0 = (w*4 + q)*64;
            gl_lds16(kt + (u0 + l)*16, &KV[slot][0][u0*8]);
            gl_lds16(vt + (u0 + l)*16, &KV[slot][1][u0*8]);
        }
    };

    stage(0, 0);

    for (int t = 0; t < NT; t++) {
        int slot = t & 1;
        __syncthreads();
        if (t+1 < NT) stage(slot^1, t+1);

        f32x16 st0, st1;
        #pragma unroll
        for (int r = 0; r < 16; r++) { st0[r] = 0.f; st1[r] = 0.f; }
        const short* kb_ = &KV[slot][0][0];
        __builtin_amdgcn_s_setprio(1);
        #pragma unroll
        for (int s = 0; s < 8; s++) {
            short8 ka = *(const short8*)(kb_ + ((size_t)((4*s   + lh)*32 + l31))*8);
            short8 kc = *(const short8*)(kb_ + ((size_t)((4*s+2 + lh)*32 + l31))*8);
            st0 = __builtin_amdgcn_mfma_f32_32x32x16_bf16(ka, qf[2*s],   st0, 0, 0, 0);
            st1 = __builtin_amdgcn_mfma_f32_32x32x16_bf16(kc, qf[2*s+1], st1, 0, 0, 0);
        }
        __builtin_amdgcn_s_setprio(0);

        float sv[16];
        #pragma unroll
        for (int r = 0; r < 16; r++) sv[r] = st0[r] + st1[r];
        float pmax = sv[0];
        #pragma unroll
        for (int r = 1; r < 16; r++) pmax = fmaxf(pmax, sv[r]);
        pmax = fmaxf(pmax, __shfl_xor(pmax, 32));
        if (!__all(pmax <= m + 8.0f)) {
            float mn = fmaxf(m, pmax);
            float fac = __expf(m - mn);
            m = mn;
            lsum *= fac;
            #pragma unroll
            for (int mc = 0; mc < 8; mc++)
                #pragma unroll
                for (int r = 0; r < 16; r++) ot[mc][r] *= fac;
        }
        float p[16]; float ls = 0.f;
        #pragma unroll
        for (int r = 0; r < 16; r++) { p[r] = __expf(sv[r] - m); ls += p[r]; }
        ls += __shfl_xor(ls, 32);
        lsum += ls;

        short8 pf0, pf1;
        {
            uint_t x0 = cvtpk_bf16(p[0], p[1]);
            uint_t y0 = cvtpk_bf16(p[4], p[5]);
            uint_t x1 = cvtpk_bf16(p[2], p[3]);
            uint_t y1 = cvtpk_bf16(p[6], p[7]);
            auto r0 = __builtin_amdgcn_permlane32_swap(x0, y0, false, false);
            auto r1 = __builtin_amdgcn_permlane32_swap(x1, y1, false, false);
            union { uint_t u[4]; short8 s8; } u_;
            u_.u[0] = r0[0]; u_.u[1] = r1[0]; u_.u[2] = r0[1]; u_.u[3] = r1[1];
            pf0 = u_.s8;
            uint_t x2 = cvtpk_bf16(p[8],  p[9]);
            uint_t y2 = cvtpk_bf16(p[12], p[13]);
            uint_t x3 = cvtpk_bf16(p[10], p[11]);
            uint_t y3 = cvtpk_bf16(p[14], p[15]);
            auto r2 = __builtin_amdgcn_permlane32_swap(x2, y2, false, false);
            auto r3 = __builtin_amdgcn_permlane32_swap(x3, y3, false, false);
            union { uint_t u[4]; short8 s8; } u2_;
            u2_.u[0] = r2[0]; u2_.u[1] = r3[0]; u2_.u[2] = r2[1]; u2_.u[3] = r3[1];
            pf1 = u2_.s8;
        }

        const short* vb_ = &KV[slot][1][0];
        __builtin_amdgcn_s_setprio(1);
        #pragma unroll
        for (int mc = 0; mc < 8; mc++) {
            short8 v0 = *(const short8*)(vb_ + ((size_t)((lh)*256   + mc*32 + l31))*8);
            short8 v1 = *(const short8*)(vb_ + ((size_t)((2+lh)*256 + mc*32 + l31))*8);
            ot[mc] = __builtin_amdgcn_mfma_f32_32x32x16_bf16(v0, pf0, ot[mc], 0, 0, 0);
            ot[mc] = __builtin_amdgcn_mfma_f32_32x32x16_bf16(v1, pf1, ot[mc], 0, 0, 0);
        }
        __builtin_amdgcn_s_setprio(0);
    }

    float invl = 1.f / lsum;
    ushort_t* pbase = part + (size_t)kvq*4194304 + ((size_t)(b*N + qbase + l31))*256;
    #pragma unroll
    for (int mc = 0; mc < 8; mc++)
        #pragma unroll
        for (int rp = 0; rp < 8; rp++) {
            int r0 = rp*2;
            uint_t wd = cvtpk_bf16(ot[mc][r0]*invl, ot[mc][r0+1]*invl);
            int c0 = (r0 & 3) + 8*(r0 >> 2) + 4*lh + 32*mc;
            *(uint_t*)(pbase + c0) = wd;
        }
    if (l < 32) {
        size_t row = (size_t)kvq*16384 + b*4096 + qbase + l;
        ml[row*2]     = m;
        ml[row*2 + 1] = lsum;
    }
}

// ---------------- K3b: merge kv-split partials ----------------
template<int NS>
__global__ __launch_bounds__(256) void attn_merge(const ushort_t* __restrict__ part,
        const float* __restrict__ ml, ushort_t* __restrict__ ob) {
    int t = blockIdx.x*256 + threadIdx.x;
    int row = t >> 5;
    int c8 = (t & 31) * 8;
    float mv[NS], lv[NS];
    float M = -INFINITY;
    #pragma unroll
    for (int i = 0; i < NS; i++) {
        mv[i] = ml[((size_t)i*16384 + row)*2];
        lv[i] = ml[((size_t)i*16384 + row)*2 + 1];
        M = fmaxf(M, mv[i]);
    }
    float wv[NS]; float wsum = 0.f;
    #pragma unroll
    for (int i = 0; i < NS; i++) { wv[i] = __expf(mv[i] - M)*lv[i]; wsum += wv[i]; }
    float inv = 1.f / wsum;
    float o[8];
    #pragma unroll
    for (int e = 0; e < 8; e++) o[e] = 0.f;
    #pragma unroll
    for (int i = 0; i < NS; i++) {
        const ushort_t* p = part + (size_t)i*4194304 + (size_t)row*256 + c8;
        float wi = wv[i]*inv;
        #pragma unroll
        for (int e = 0; e < 8; e++) o[e] += wi*bf2f(p[e]);
    }
    uint4 pk;
    pk.x = pack2(o[0], o[1]);
    pk.y = pack2(o[2], o[3]);
    pk.z = pack2(o[4], o[5]);
    pk.w = pack2(o[6], o[7]);
    *(uint4*)(ob + (size_t)row*256 + c8) = pk;
}

// ---------------- K4: proj GEMM bf16 MFMA + bias + residual (BN=64, 2 blk/CU) ----------------
__global__ __launch_bounds__(256) void proj_mfma(const ushort_t* __restrict__ obf,
        const ushort_t* __restrict__ wpbf, const float* __restrict__ bp,
        const float* __restrict__ x, float* __restrict__ out) {
    int b = blockIdx.z, o0 = blockIdx.y*128, n0 = blockIdx.x*64;
    int tid = threadIdx.x;
    int w = tid>>6, l = tid&63, l31 = l&31, lh = l>>5;
    __shared__ short Ws[2][8192];
    __shared__ short Hs[2][4096];

    const ushort_t* wb = wpbf + (size_t)o0*256;
    const ushort_t* hb = obf + ((size_t)b*N + n0)*256;

    auto stage = [&](int bb, int c0) {
        #pragma unroll
        for (int q = 0; q < 4; q++) {
            int u0 = (q*4 + w)*64;
            int u  = u0 + l;
            int row = u & 127, ch = u >> 7;
            gl_lds16(wb + (size_t)row*256 + c0 + ch*8, &Ws[bb][u0*8]);
        }
        #pragma unroll
        for (int q = 0; q < 2; q++) {
            int u0 = (q*4 + w)*64;
            int u  = u0 + l;
            int row = u & 63, ch = u >> 6;
            gl_lds16(hb + (size_t)row*256 + c0 + ch*8, &Hs[bb][u0*8]);
        }
    };

    f32x16 acc[2];
    #pragma unroll
    for (int nf = 0; nf < 2; nf++)
        #pragma unroll
        for (int r = 0; r < 16; r++) acc[nf][r] = 0.f;

    stage(0, 0);
    __syncthreads();
    for (int t = 0; t < 4; t++) {
        int bb = t & 1;
        if (t < 3) stage(bb^1, (t+1)*64);
        short8 af[4];
        #pragma unroll
        for (int s = 0; s < 4; s++)
            af[s] = *(const short8*)&Ws[bb][((2*s+lh)*128 + w*32 + l31)*8];
        #pragma unroll
        for (int nf = 0; nf < 2; nf++) {
            #pragma unroll
            for (int s = 0; s < 4; s++) {
                short8 hf = *(const short8*)&Hs[bb][((2*s+lh)*64 + nf*32 + l31)*8];
                acc[nf] = __builtin_amdgcn_mfma_f32_32x32x16_bf16(af[s], hf, acc[nf], 0, 0, 0);
            }
        }
        __syncthreads();
    }

    int cw = o0 + w*32;
    float bv[16];
    #pragma unroll
    for (int r = 0; r < 16; r++) bv[r] = bp[cw + (r&3) + 8*(r>>2) + 4*lh];

    #pragma unroll
    for (int nf = 0; nf < 2; nf++) {
        int n = n0 + nf*32 + l31;
        #pragma unroll
        for (int r = 0; r < 16; r++) {
            int cl = (r&3) + 8*(r>>2) + 4*lh;
            size_t a = ((size_t)b*C + cw + cl)*N + n;
            out[a] = acc[nf][r] + bv[r] + x[a];
        }
    }
}

extern "C" void kernel_launch(void* const* d_in, const int* in_sizes, int n_in,
                              void* d_out, int out_size, void* d_ws, size_t ws_size,
                              hipStream_t stream) {
    const float* x      = (const float*)d_in[0];
    const float* gamma  = (const float*)d_in[1];
    const float* beta   = (const float*)d_in[2];
    const float* w_qkv  = (const float*)d_in[3];
    const float* b_qkv  = (const float*)d_in[4];
    const float* w_proj = (const float*)d_in[5];
    const float* b_proj = (const float*)d_in[6];
    float* out = (float*)d_out;
    char* wsb  = (char*)d_ws;

    const size_t MB = 1048576;
    ushort_t* qbf  = (ushort_t*)(wsb);                       // 8 MB
    ushort_t* kimg = (ushort_t*)(wsb + 8*MB);                // 8 MB (LDS-image tiles)
    ushort_t* vimg = (ushort_t*)(wsb + 16*MB);               // 8 MB (LDS-image tiles)
    ushort_t* part = (ushort_t*)(wsb + 24*MB);               // 32 MB (4 quarters)
    float*    ml   = (float*)  (wsb + 56*MB);                // 512 KB
    ushort_t* ob   = (ushort_t*)(wsb + 56*MB + 524288);      // 8 MB
    float* partials = (float*) (wsb + 64*MB + 524288);       // 2 KB
    float* stats    = partials + 512;
    ushort_t* wbf  = (ushort_t*)(wsb + 64*MB + 524288 + 4096); // 512 KB

    gn_wconv<<<dim3(320), dim3(256), 0, stream>>>(x, partials, w_qkv, w_proj, wbf);
    gn_final<<<dim3(1), dim3(64), 0, stream>>>(partials, stats);
    qkv_fused<<<dim3(32, 6, 4), dim3(256), 0, stream>>>(x, wbf, gamma, beta, stats, b_qkv, qbf, kimg, vimg);
    attn_mfma<<<dim3(512), dim3(256), 0, stream>>>(qbf, kimg, vimg, part, ml);
    attn_merge<4><<<dim3(2048), dim3(256), 0, stream>>>(part, ml, ob);
    proj_mfma<<<dim3(64, 2, 4), dim3(256), 0, stream>>>(ob, wbf + 196608, b_proj, x, out);
}